// Round 2
// 665.221 us; speedup vs baseline: 1.0620x; 1.0620x over previous
//
#include <hip/hip_runtime.h>
#include <hip/hip_fp16.h>

#define BATCH   65536
#define IN_DIM  784
#define KPAD    800      // padded K per half (hi or lo)
#define K2      1600     // total GEMM K = [hi | lo]
#define H_DIM   1024
#define C_DIM   10
#define BN_EPS  1e-5f
#define NT      (K2 / 32)   // 50 K-tiles of 32 halves

typedef _Float16 half8 __attribute__((ext_vector_type(8)));
typedef _Float16 half4 __attribute__((ext_vector_type(4)));
typedef float    f32x4 __attribute__((ext_vector_type(4)));

#if defined(__has_builtin)
#if __has_builtin(__builtin_amdgcn_global_load_lds)
#define HAVE_ASYNC 1
#endif
#endif
#ifndef HAVE_ASYNC
#define HAVE_ASYNC 0
#endif

// Stage 16B/lane from global into LDS. Async path: wave-uniform LDS base,
// HW scatters lane i -> base + i*16 (layout contiguous in lane order).
__device__ __forceinline__ void stage16(const _Float16* g, _Float16* ldsBase, int lane) {
#if HAVE_ASYNC
  __builtin_amdgcn_global_load_lds((const __attribute__((address_space(1))) void*)g,
                                   (__attribute__((address_space(3))) void*)ldsBase,
                                   16, 0, 0);
#else
  *(half8*)(ldsBase + lane * 8) = *(const half8*)g;
#endif
}

// ---------------------------------------------------------------------------
// K1: split x (fp32) into fp16 hi/lo halves, K-concatenated:
//     X2[b] = [hi(784) 0pad | lo(784) 0pad]
// ---------------------------------------------------------------------------
__global__ __launch_bounds__(256) void split_x(const float* __restrict__ x,
                                               _Float16* __restrict__ X2) {
  const long tid = (long)blockIdx.x * 256 + threadIdx.x;   // BATCH*200 threads
  const long row = tid / 200;
  const int  q   = (int)(tid - row * 200);
  const int  k   = q * 4;
  half4 hi = {}, lo = {};
  if (k < IN_DIM) {                       // 784 = 4*196, exact
    const f32x4 v = *(const f32x4*)&x[row * IN_DIM + k];
#pragma unroll
    for (int i = 0; i < 4; ++i) {
      const _Float16 h = (_Float16)v[i];
      hi[i] = h;
      lo[i] = (_Float16)(v[i] - (float)h);
    }
  }
  _Float16* dst = X2 + row * K2 + k;
  *(half4*)dst = hi;
  *(half4*)(dst + KPAD) = lo;
}

// ---------------------------------------------------------------------------
// K2: weight prep. Blocks 0..1023: alpha1[j]=mean|w1[j]|, S2[j]=[sign|0pad|sign|0pad] fp16.
//     Blocks 1024..1033: bw2[c][j] = mean|w2[c]| * sign(w2[c][j]) fp32.
// ---------------------------------------------------------------------------
__global__ __launch_bounds__(256) void prep_w(const float* __restrict__ w1,
                                              const float* __restrict__ w2,
                                              float* __restrict__ alpha1,
                                              _Float16* __restrict__ S2,
                                              float* __restrict__ bw2) {
  __shared__ float red[4];
  const int tid = threadIdx.x, lane = tid & 63, wave = tid >> 6;
  const int j = blockIdx.x;
  if (j < H_DIM) {
    const float* wr = w1 + (long)j * IN_DIM;
    float s = 0.f;
    for (int k = tid; k < IN_DIM; k += 256) s += fabsf(wr[k]);
#pragma unroll
    for (int off = 32; off > 0; off >>= 1) s += __shfl_xor(s, off, 64);
    if (lane == 0) red[wave] = s;
    __syncthreads();
    if (tid == 0) alpha1[j] = (red[0] + red[1] + red[2] + red[3]) * (1.f / IN_DIM);
    _Float16* dr = S2 + (long)j * K2;
    for (int k = tid; k < KPAD; k += 256) {
      const float v = (k < IN_DIM) ? wr[k] : 0.f;
      const _Float16 sg = (_Float16)((v > 0.f) ? 1.f : ((v < 0.f) ? -1.f : 0.f));
      dr[k] = sg;
      dr[KPAD + k] = sg;
    }
  } else {
    const int c = j - H_DIM;
    const float* wr = w2 + (long)c * H_DIM;
    float s = 0.f;
    for (int k = tid; k < H_DIM; k += 256) s += fabsf(wr[k]);
#pragma unroll
    for (int off = 32; off > 0; off >>= 1) s += __shfl_xor(s, off, 64);
    if (lane == 0) red[wave] = s;
    __syncthreads();
    const float alpha = (red[0] + red[1] + red[2] + red[3]) * (1.f / H_DIM);
    for (int k = tid; k < H_DIM; k += 256) {
      const float v = wr[k];
      const float sg = (v > 0.f) ? 1.f : ((v < 0.f) ? -1.f : 0.f);
      bw2[(long)c * H_DIM + k] = alpha * sg;
    }
  }
}

// ---------------------------------------------------------------------------
// K3: GEMM1  H[b][j] = alpha1[j] * sum_k X2[b][k]*S2[j][k]   (M=65536,N=1024,K=1600)
//
// R5 (= R4 + endpgm-drain fix): 256x256 tile, 8 waves, BK=32, 4-slot LDS ring
// (128 KiB), deep pipeline:
//  - counted vmcnt(8): tiles t+1,t+2 stay in flight across the barrier (T4);
//    tile t+3 is issued during tile t.
//  - raw s_barrier (no vmcnt(0) drain), 2 per tile; asm "" memory fence after
//    the top barrier pins the frag ds_reads below it.
//  - Safety: slot (t+3)&3 == (t-1)&3 was last READ in tile t-1; every wave's
//    reads of it complete (lgkmcnt before its MFMAs) before it arrives at the
//    top-of-t barrier, and stages are issued after that barrier -> no race.
//    vmcnt(8)+barrier at top of t => tile t landed for ALL waves.
//  - NEW: drain vmcnt(0) after the K-loop. Otherwise up to 8 LDS-DMA writes
//    are still in flight at s_endpgm and can land in LDS after it has been
//    reassigned to a new workgroup (corrupting its staged tiles).
//  - setprio(1) around each 16-MFMA cluster (T5).
//  - swizzle (verified R2, conflict=0): source chunk (lane&3)^((lane>>3)&3),
//    read chunk kc^((fr>>1)&3); LDS stays linear for global_load_lds.
//  - XCD remap: 1024 blocks, b%8=XCD, n-tile fastest within XCD so the 4
//    blocks sharing an A-panel are co-resident on one L2.
// ---------------------------------------------------------------------------
__global__ __launch_bounds__(512, 2) void gemm1(const _Float16* __restrict__ X2,
                                                const _Float16* __restrict__ S2,
                                                const float* __restrict__ alpha1,
                                                float* __restrict__ H,
                                                float* __restrict__ colsum,
                                                float* __restrict__ colsumsq) {
  __shared__ _Float16 lds[4 * 16384];   // 4 slots x (A 256x32 | B 256x32) fp16 = 128 KiB
  const int tid  = threadIdx.x;
  const int lane = tid & 63;
  const int w    = tid >> 6;            // wave 0..7
  const int wr   = w >> 2;              // 0..1  (M dir, 128 rows each)
  const int wc   = w & 3;               // 0..3  (N dir, 64 cols each)

  // XCD-aware remap: 1024 blocks -> (mt 0..255, nt 0..3), nt fastest per XCD.
  const int b     = blockIdx.x;
  const int xcd   = b & 7;
  const int local = b >> 3;                       // 0..127
  const long m0   = (long)(xcd * 32 + (local >> 2)) * 256;
  const int  n0   = (local & 3) * 256;

  // staging: swizzled global source chunk per lane, linear LDS dest
  const int c8 = ((lane & 3) ^ ((lane >> 3) & 3)) * 8;
  const _Float16* aG = X2 + (m0 + w * 32 + (lane >> 2)) * K2 + c8;
  const _Float16* bG = S2 + (long)(n0 + w * 32 + (lane >> 2)) * K2 + c8;
  const int ldsW0 = (w * 32) * 32;                // wave's staging rows (halves)
  const int ldsW1 = (w * 32 + 16) * 32;

  // read-side frag offsets (same swizzle family, verified conflict-free)
  const int fr = lane & 15;                       // n (B) / m (A) within 16
  const int kc = lane >> 4;                       // K 16B-chunk index
  const int cp = (kc ^ ((fr >> 1) & 3)) * 8;
  const int aoff = (wr * 128 + fr) * 32 + cp;     // + mi*512
  const int boff = (wc * 64 + fr) * 32 + cp;      // + ni*512

  f32x4 acc[8][4] = {};

  // prologue: stage tiles 0..2 (12 loads/thread in flight)
#pragma unroll
  for (int kt = 0; kt < 3; ++kt) {
    _Float16* Ap = &lds[kt * 16384];
    _Float16* Bp = Ap + 8192;
    stage16(aG + kt * 32, Ap + ldsW0, lane);
    stage16(aG + 16 * K2 + kt * 32, Ap + ldsW1, lane);
    stage16(bG + kt * 32, Bp + ldsW0, lane);
    stage16(bG + 16 * K2 + kt * 32, Bp + ldsW1, lane);
  }

  for (int t = 0; t < NT; ++t) {
    _Float16* Asl = &lds[(t & 3) * 16384];
    _Float16* Bsl = Asl + 8192;
    const int ks = (t + 3 < NT) ? (t + 3) * 32 : (NT - 1) * 32;  // clamp keeps counts uniform
    _Float16* Ap = &lds[((t + 3) & 3) * 16384];
    _Float16* Bp = Ap + 8192;

    // tile-boundary: tile t guaranteed in LDS; tiles t+1,t+2 stay in flight
    asm volatile("s_waitcnt vmcnt(8)" ::: "memory");
    __builtin_amdgcn_s_barrier();
    asm volatile("" ::: "memory");   // keep frag loads below the barrier

    half8 af[4], bf[4];
    // ---- phase a: B frags + A frags (mi 0..3); stage A of tile t+3
#pragma unroll
    for (int ni = 0; ni < 4; ++ni) bf[ni] = *(const half8*)&Bsl[boff + ni * 512];
#pragma unroll
    for (int mi = 0; mi < 4; ++mi) af[mi] = *(const half8*)&Asl[aoff + mi * 512];
    stage16(aG + ks, Ap + ldsW0, lane);
    stage16(aG + 16 * K2 + ks, Ap + ldsW1, lane);
    __builtin_amdgcn_s_setprio(1);
#pragma unroll
    for (int mi = 0; mi < 4; ++mi)
#pragma unroll
      for (int ni = 0; ni < 4; ++ni)
        acc[mi][ni] = __builtin_amdgcn_mfma_f32_16x16x32_f16(af[mi], bf[ni], acc[mi][ni], 0, 0, 0);
    __builtin_amdgcn_s_setprio(0);
    __builtin_amdgcn_s_barrier();

    // ---- phase b: A frags (mi 4..7), B reused; stage B of tile t+3
#pragma unroll
    for (int mi = 0; mi < 4; ++mi) af[mi] = *(const half8*)&Asl[aoff + (mi + 4) * 512];
    stage16(bG + ks, Bp + ldsW0, lane);
    stage16(bG + 16 * K2 + ks, Bp + ldsW1, lane);
    __builtin_amdgcn_s_setprio(1);
#pragma unroll
    for (int mi = 0; mi < 4; ++mi)
#pragma unroll
      for (int ni = 0; ni < 4; ++ni)
        acc[mi + 4][ni] = __builtin_amdgcn_mfma_f32_16x16x32_f16(af[mi], bf[ni], acc[mi + 4][ni], 0, 0, 0);
    __builtin_amdgcn_s_setprio(0);
  }

  // Drain in-flight LDS-DMA before epilogue/endpgm: late DMA landing after LDS
  // is reassigned to a new workgroup would corrupt that block's tiles.
  asm volatile("s_waitcnt vmcnt(0)" ::: "memory");

  // epilogue: D layout col=lane&15, row=(lane>>4)*4+r  [measured m89/m91]
  // + fused column sum/sumsq
  const int rq = (lane >> 4) * 4;
#pragma unroll
  for (int ni = 0; ni < 4; ++ni) {
    const int col = n0 + wc * 64 + ni * 16 + fr;
    const float a1 = alpha1[col];
    float s = 0.f, q = 0.f;
#pragma unroll
    for (int mi = 0; mi < 8; ++mi) {
#pragma unroll
      for (int r = 0; r < 4; ++r) {
        const long row = m0 + wr * 128 + mi * 16 + rq + r;
        const float v = acc[mi][ni][r] * a1;
        H[row * H_DIM + col] = v;
        s += v;
        q += v * v;
      }
    }
    s += __shfl_xor(s, 16, 64);
    s += __shfl_xor(s, 32, 64);
    q += __shfl_xor(q, 16, 64);
    q += __shfl_xor(q, 32, 64);
    if ((lane >> 4) == 0) {
      atomicAdd(&colsum[col], s);
      atomicAdd(&colsumsq[col], q);
    }
  }
}

// ---------------------------------------------------------------------------
// K5: normalize -> sign -> out = a @ bw2^T.  Lane-per-row + LDS broadcast.
// All lanes of a wave walk the same column chunk j4 -> w2s/cs/ts reads are
// uniform-address LDS broadcasts (free). No shuffles; per-lane sequential row
// walk stays in L1. HBM-bound on the 268 MB H read.
// ---------------------------------------------------------------------------
__global__ __launch_bounds__(256) void final_k(const float* __restrict__ H,
                                               const float* __restrict__ colsum,
                                               const float* __restrict__ colsumsq,
                                               const float* __restrict__ gamma,
                                               const float* __restrict__ beta,
                                               const float* __restrict__ bw2,
                                               float* __restrict__ out) {
  __shared__ float cs[H_DIM], ts[H_DIM];
  __shared__ float w2s[C_DIM * H_DIM];   // [oc][j]
  const int tid = threadIdx.x, lane = tid & 63, wave = tid >> 6;
  for (int j = tid; j < H_DIM; j += 256) {
    const float mu  = colsum[j] * (1.f / BATCH);
    const float var = colsumsq[j] * (1.f / BATCH) - mu * mu;  // biased var
    const float c   = gamma[j] * rsqrtf(var + BN_EPS);
    cs[j] = c;
    ts[j] = beta[j] - c * mu;             // sign(gamma*(h-mu)*invstd+beta) = sign(c*h+t)
  }
  for (int i = tid; i < C_DIM * H_DIM; i += 256) w2s[i] = bw2[i];
  __syncthreads();

  const long row = (long)blockIdx.x * 256 + wave * 64 + lane;  // grid = BATCH/256
  const float* hr = H + row * H_DIM;
  float p[C_DIM] = {};
#pragma unroll 8
  for (int j4 = 0; j4 < H_DIM / 4; ++j4) {
    const f32x4 v  = *(const f32x4*)&hr[j4 * 4];
    const f32x4 cv = *(const f32x4*)&cs[j4 * 4];   // broadcast
    const f32x4 tv = *(const f32x4*)&ts[j4 * 4];   // broadcast
    f32x4 a;
#pragma unroll
    for (int i = 0; i < 4; ++i) {
      const float hv = v[i] * cv[i] + tv[i];
      a[i] = (hv > 0.f) ? 1.f : ((hv < 0.f) ? -1.f : 0.f);   // jnp.sign semantics
    }
#pragma unroll
    for (int oc = 0; oc < C_DIM; ++oc) {
      const f32x4 wv = *(const f32x4*)&w2s[oc * H_DIM + j4 * 4];  // broadcast
      p[oc] += a[0] * wv[0] + a[1] * wv[1] + a[2] * wv[2] + a[3] * wv[3];
    }
  }
  float* orow = out + row * C_DIM;
#pragma unroll
  for (int oc = 0; oc < C_DIM; ++oc) orow[oc] = p[oc];
}

// ---------------------------------------------------------------------------
extern "C" void kernel_launch(void* const* d_in, const int* in_sizes, int n_in,
                              void* d_out, int out_size, void* d_ws, size_t ws_size,
                              hipStream_t stream) {
  const float* x     = (const float*)d_in[0];
  const float* w1    = (const float*)d_in[1];
  const float* w2    = (const float*)d_in[2];
  const float* gamma = (const float*)d_in[3];
  const float* beta  = (const float*)d_in[4];
  float* out = (float*)d_out;

  // workspace layout (bytes), all 256B-aligned offsets; total ~481.5 MB
  char* ws = (char*)d_ws;
  _Float16* X2     = (_Float16*)(ws + 0);            // 65536*1600*2 = 209,715,200
  float*    H      = (float*)  (ws + 209715200LL);   // 65536*1024*4 = 268,435,456
  _Float16* S2     = (_Float16*)(ws + 478150656LL);  // 1024*1600*2  =   3,276,800
  float*    BW2    = (float*)  (ws + 481427456LL);   // 10*1024*4    =      40,960
  float*    ALPHA1 = (float*)  (ws + 481468416LL);   // 1024*4       =       4,096
  float*    COLS   = (float*)  (ws + 481472512LL);   // 1024*4
  float*    COLQ   = (float*)  (ws + 481476608LL);   // 1024*4 (contiguous w/ COLS)

  hipMemsetAsync(COLS, 0, 2 * H_DIM * sizeof(float), stream);  // ws is poisoned each call
  split_x<<<(BATCH * 200) / 256, 256, 0, stream>>>(x, X2);
  prep_w<<<H_DIM + C_DIM, 256, 0, stream>>>(w1, w2, ALPHA1, S2, BW2);
  gemm1<<<1024, 512, 0, stream>>>(X2, S2, ALPHA1, H, COLS, COLQ);
  final_k<<<BATCH / 256, 256, 0, stream>>>(H, COLS, COLQ, gamma, beta, BW2, out);
}

// Round 3
// 615.026 us; speedup vs baseline: 1.1486x; 1.0816x over previous
//
#include <hip/hip_runtime.h>
#include <hip/hip_fp16.h>

#define BATCH   65536
#define IN_DIM  784
#define KPAD    800      // padded K per half (hi or lo)
#define K2      1600     // total GEMM K = [hi | lo]
#define H_DIM   1024
#define C_DIM   10
#define BN_EPS  1e-5f
#define NT      (K2 / 32)   // 50 K-tiles of 32 halves

typedef _Float16 half8 __attribute__((ext_vector_type(8)));
typedef _Float16 half4 __attribute__((ext_vector_type(4)));
typedef float    f32x4 __attribute__((ext_vector_type(4)));

#if defined(__has_builtin)
#if __has_builtin(__builtin_amdgcn_global_load_lds)
#define HAVE_ASYNC 1
#endif
#endif
#ifndef HAVE_ASYNC
#define HAVE_ASYNC 0
#endif

// Stage 16B/lane from global into LDS. Async path: wave-uniform LDS base,
// HW scatters lane i -> base + i*16 (layout contiguous in lane order).
__device__ __forceinline__ void stage16(const _Float16* g, _Float16* ldsBase, int lane) {
#if HAVE_ASYNC
  __builtin_amdgcn_global_load_lds((const __attribute__((address_space(1))) void*)g,
                                   (__attribute__((address_space(3))) void*)ldsBase,
                                   16, 0, 0);
#else
  *(half8*)(ldsBase + lane * 8) = *(const half8*)g;
#endif
}

// ---------------------------------------------------------------------------
// K1: split x (fp32) into fp16 hi/lo halves, K-concatenated:
//     X2[b] = [hi(784) 0pad | lo(784) 0pad]
// ---------------------------------------------------------------------------
__global__ __launch_bounds__(256) void split_x(const float* __restrict__ x,
                                               _Float16* __restrict__ X2) {
  const long tid = (long)blockIdx.x * 256 + threadIdx.x;   // BATCH*200 threads
  const long row = tid / 200;
  const int  q   = (int)(tid - row * 200);
  const int  k   = q * 4;
  half4 hi = {}, lo = {};
  if (k < IN_DIM) {                       // 784 = 4*196, exact
    const f32x4 v = *(const f32x4*)&x[row * IN_DIM + k];
#pragma unroll
    for (int i = 0; i < 4; ++i) {
      const _Float16 h = (_Float16)v[i];
      hi[i] = h;
      lo[i] = (_Float16)(v[i] - (float)h);
    }
  }
  _Float16* dst = X2 + row * K2 + k;
  *(half4*)dst = hi;
  *(half4*)(dst + KPAD) = lo;
}

// ---------------------------------------------------------------------------
// K2: weight prep. Blocks 0..1023: alpha1[j]=mean|w1[j]|, S2[j]=[sign|0pad|sign|0pad] fp16.
//     Blocks 1024..1033: bw2[c][j] = mean|w2[c]| * sign(w2[c][j]) fp32.
// ---------------------------------------------------------------------------
__global__ __launch_bounds__(256) void prep_w(const float* __restrict__ w1,
                                              const float* __restrict__ w2,
                                              float* __restrict__ alpha1,
                                              _Float16* __restrict__ S2,
                                              float* __restrict__ bw2) {
  __shared__ float red[4];
  const int tid = threadIdx.x, lane = tid & 63, wave = tid >> 6;
  const int j = blockIdx.x;
  if (j < H_DIM) {
    const float* wr = w1 + (long)j * IN_DIM;
    float s = 0.f;
    for (int k = tid; k < IN_DIM; k += 256) s += fabsf(wr[k]);
#pragma unroll
    for (int off = 32; off > 0; off >>= 1) s += __shfl_xor(s, off, 64);
    if (lane == 0) red[wave] = s;
    __syncthreads();
    if (tid == 0) alpha1[j] = (red[0] + red[1] + red[2] + red[3]) * (1.f / IN_DIM);
    _Float16* dr = S2 + (long)j * K2;
    for (int k = tid; k < KPAD; k += 256) {
      const float v = (k < IN_DIM) ? wr[k] : 0.f;
      const _Float16 sg = (_Float16)((v > 0.f) ? 1.f : ((v < 0.f) ? -1.f : 0.f));
      dr[k] = sg;
      dr[KPAD + k] = sg;
    }
  } else {
    const int c = j - H_DIM;
    const float* wr = w2 + (long)c * H_DIM;
    float s = 0.f;
    for (int k = tid; k < H_DIM; k += 256) s += fabsf(wr[k]);
#pragma unroll
    for (int off = 32; off > 0; off >>= 1) s += __shfl_xor(s, off, 64);
    if (lane == 0) red[wave] = s;
    __syncthreads();
    const float alpha = (red[0] + red[1] + red[2] + red[3]) * (1.f / H_DIM);
    for (int k = tid; k < H_DIM; k += 256) {
      const float v = wr[k];
      const float sg = (v > 0.f) ? 1.f : ((v < 0.f) ? -1.f : 0.f);
      bw2[(long)c * H_DIM + k] = alpha * sg;
    }
  }
}

// ---------------------------------------------------------------------------
// K3: GEMM1  H[b][j] = alpha1[j] * sum_k X2[b][k]*S2[j][k]   (M=65536,N=1024,K=1600)
//
// R6 (= R5 with 5-slot ring): 256x256 tile, 8 waves, BK=32, 5-slot LDS ring
// (163840 B = full 160 KiB pool; AITER fmha precedent for 160KB/workgroup).
//  - lead-4 prefetch: prologue stages tiles 0..3; tile t+4 issued during t.
//  - counted vmcnt(12): at top of t, 16 outstanding -> retire exactly tile
//    t's 4 loads (in-order), tiles t+1..t+3 stay in flight (cover ~3 tiles
//    ~1.9k cyc vs L3-hit staging latency ~500-700 cyc + queuing).
//  - stage-issue FIRST in each phase (issue-early, T14), frag ds_reads after.
//  - Safety: slot (t+4)%5 == (t-1)%5 was last READ in tile t-1; every wave's
//    reads of it complete (lgkmcnt before its MFMAs) before it arrives at the
//    top-of-t barrier, and stages are issued after that barrier -> no race.
//    vmcnt(12)+barrier at top of t => tile t landed for ALL waves.
//  - drain vmcnt(0) after the K-loop (LDS-DMA must not outlive the block).
//  - setprio(1) around each 16-MFMA cluster (T5).
//  - swizzle (verified R2, conflict=0): source chunk (lane&3)^((lane>>3)&3),
//    read chunk kc^((fr>>1)&3); LDS stays linear for global_load_lds.
//  - XCD remap: 1024 blocks, b%8=XCD, n-tile fastest within XCD.
// ---------------------------------------------------------------------------
__global__ __launch_bounds__(512, 2) void gemm1(const _Float16* __restrict__ X2,
                                                const _Float16* __restrict__ S2,
                                                const float* __restrict__ alpha1,
                                                float* __restrict__ H,
                                                float* __restrict__ colsum,
                                                float* __restrict__ colsumsq) {
  __shared__ _Float16 lds[5 * 16384];   // 5 slots x (A 256x32 | B 256x32) fp16 = 160 KiB
  const int tid  = threadIdx.x;
  const int lane = tid & 63;
  const int w    = tid >> 6;            // wave 0..7
  const int wr   = w >> 2;              // 0..1  (M dir, 128 rows each)
  const int wc   = w & 3;               // 0..3  (N dir, 64 cols each)

  // XCD-aware remap: 1024 blocks -> (mt 0..255, nt 0..3), nt fastest per XCD.
  const int b     = blockIdx.x;
  const int xcd   = b & 7;
  const int local = b >> 3;                       // 0..127
  const long m0   = (long)(xcd * 32 + (local >> 2)) * 256;
  const int  n0   = (local & 3) * 256;

  // staging: swizzled global source chunk per lane, linear LDS dest
  const int c8 = ((lane & 3) ^ ((lane >> 3) & 3)) * 8;
  const _Float16* aG = X2 + (m0 + w * 32 + (lane >> 2)) * K2 + c8;
  const _Float16* bG = S2 + (long)(n0 + w * 32 + (lane >> 2)) * K2 + c8;
  const int ldsW0 = (w * 32) * 32;                // wave's staging rows (halves)
  const int ldsW1 = (w * 32 + 16) * 32;

  // read-side frag offsets (same swizzle family, verified conflict-free)
  const int fr = lane & 15;                       // n (B) / m (A) within 16
  const int kc = lane >> 4;                       // K 16B-chunk index
  const int cp = (kc ^ ((fr >> 1) & 3)) * 8;
  const int aoff = (wr * 128 + fr) * 32 + cp;     // + mi*512
  const int boff = (wc * 64 + fr) * 32 + cp;      // + ni*512

  f32x4 acc[8][4] = {};

  // prologue: stage tiles 0..3 (16 loads/thread in flight)
#pragma unroll
  for (int kt = 0; kt < 4; ++kt) {
    _Float16* Ap = &lds[kt * 16384];
    _Float16* Bp = Ap + 8192;
    stage16(aG + kt * 32, Ap + ldsW0, lane);
    stage16(aG + 16 * K2 + kt * 32, Ap + ldsW1, lane);
    stage16(bG + kt * 32, Bp + ldsW0, lane);
    stage16(bG + 16 * K2 + kt * 32, Bp + ldsW1, lane);
  }

  int scur = 0;   // slot holding tile t
  int spre = 4;   // slot receiving tile t+4
  for (int t = 0; t < NT; ++t) {
    _Float16* Asl = &lds[scur * 16384];
    _Float16* Bsl = Asl + 8192;
    const int ks = (t + 4 < NT) ? (t + 4) * 32 : (NT - 1) * 32;  // clamp keeps counts uniform
    _Float16* Ap = &lds[spre * 16384];
    _Float16* Bp = Ap + 8192;

    // tile-boundary: tile t guaranteed in LDS; tiles t+1..t+3 stay in flight
    asm volatile("s_waitcnt vmcnt(12)" ::: "memory");
    __builtin_amdgcn_s_barrier();
    asm volatile("" ::: "memory");   // keep frag loads below the barrier

    // ---- phase a: issue A-stage of t+4 first, then frags, then MFMA
    stage16(aG + ks, Ap + ldsW0, lane);
    stage16(aG + 16 * K2 + ks, Ap + ldsW1, lane);
    half8 af[4], bf[4];
#pragma unroll
    for (int ni = 0; ni < 4; ++ni) bf[ni] = *(const half8*)&Bsl[boff + ni * 512];
#pragma unroll
    for (int mi = 0; mi < 4; ++mi) af[mi] = *(const half8*)&Asl[aoff + mi * 512];
    __builtin_amdgcn_s_setprio(1);
#pragma unroll
    for (int mi = 0; mi < 4; ++mi)
#pragma unroll
      for (int ni = 0; ni < 4; ++ni)
        acc[mi][ni] = __builtin_amdgcn_mfma_f32_16x16x32_f16(af[mi], bf[ni], acc[mi][ni], 0, 0, 0);
    __builtin_amdgcn_s_setprio(0);
    __builtin_amdgcn_s_barrier();

    // ---- phase b: issue B-stage of t+4, A frags (mi 4..7), B reused
    stage16(bG + ks, Bp + ldsW0, lane);
    stage16(bG + 16 * K2 + ks, Bp + ldsW1, lane);
#pragma unroll
    for (int mi = 0; mi < 4; ++mi) af[mi] = *(const half8*)&Asl[aoff + (mi + 4) * 512];
    __builtin_amdgcn_s_setprio(1);
#pragma unroll
    for (int mi = 0; mi < 4; ++mi)
#pragma unroll
      for (int ni = 0; ni < 4; ++ni)
        acc[mi + 4][ni] = __builtin_amdgcn_mfma_f32_16x16x32_f16(af[mi], bf[ni], acc[mi + 4][ni], 0, 0, 0);
    __builtin_amdgcn_s_setprio(0);

    scur = (scur == 4) ? 0 : scur + 1;
    spre = (spre == 4) ? 0 : spre + 1;
  }

  // Drain in-flight LDS-DMA before epilogue/endpgm: late DMA landing after LDS
  // is reassigned to a new workgroup would corrupt that block's tiles.
  asm volatile("s_waitcnt vmcnt(0)" ::: "memory");

  // epilogue: D layout col=lane&15, row=(lane>>4)*4+r  [measured m89/m91]
  // + fused column sum/sumsq
  const int rq = (lane >> 4) * 4;
#pragma unroll
  for (int ni = 0; ni < 4; ++ni) {
    const int col = n0 + wc * 64 + ni * 16 + fr;
    const float a1 = alpha1[col];
    float s = 0.f, q = 0.f;
#pragma unroll
    for (int mi = 0; mi < 8; ++mi) {
#pragma unroll
      for (int r = 0; r < 4; ++r) {
        const long row = m0 + wr * 128 + mi * 16 + rq + r;
        const float v = acc[mi][ni][r] * a1;
        H[row * H_DIM + col] = v;
        s += v;
        q += v * v;
      }
    }
    s += __shfl_xor(s, 16, 64);
    s += __shfl_xor(s, 32, 64);
    q += __shfl_xor(q, 16, 64);
    q += __shfl_xor(q, 32, 64);
    if ((lane >> 4) == 0) {
      atomicAdd(&colsum[col], s);
      atomicAdd(&colsumsq[col], q);
    }
  }
}

// ---------------------------------------------------------------------------
// K5: normalize -> sign -> out = a @ bw2^T.
// R6: wave-per-row, w2/cs/ts fully in REGISTERS (statically indexed: 160+32
// VGPR), no LDS, no syncthreads. Lane covers cols {c4*256+lane*4}, c4=0..3 ->
// H loads are 1KB/wave fully-coalesced. 2048 blocks x 4 waves x 8 rows.
// launch_bounds(256,2) -> 256-VGPR cap, 8 waves/CU; 4 independent loads in
// flight per row (~32KB/CU) saturates this CU's HBM share (Little's law ~6KB).
// ---------------------------------------------------------------------------
__global__ __launch_bounds__(256, 2) void final_k(const float* __restrict__ H,
                                                  const float* __restrict__ colsum,
                                                  const float* __restrict__ colsumsq,
                                                  const float* __restrict__ gamma,
                                                  const float* __restrict__ beta,
                                                  const float* __restrict__ bw2,
                                                  float* __restrict__ out) {
  const int tid = threadIdx.x, lane = tid & 63, wave = tid >> 6;
  f32x4 w2r[4][C_DIM];
  f32x4 csr[4], tsr[4];
#pragma unroll
  for (int c4 = 0; c4 < 4; ++c4) {
    const int col = c4 * 256 + lane * 4;
    const f32x4 s  = *(const f32x4*)&colsum[col];
    const f32x4 q  = *(const f32x4*)&colsumsq[col];
    const f32x4 g  = *(const f32x4*)&gamma[col];
    const f32x4 bt = *(const f32x4*)&beta[col];
    f32x4 c, t;
#pragma unroll
    for (int i = 0; i < 4; ++i) {
      const float mu  = s[i] * (1.f / BATCH);
      const float var = q[i] * (1.f / BATCH) - mu * mu;  // biased var
      c[i] = g[i] * rsqrtf(var + BN_EPS);
      t[i] = bt[i] - c[i] * mu;        // sign(gamma*(h-mu)*invstd+beta) = sign(c*h+t)
    }
    csr[c4] = c;
    tsr[c4] = t;
#pragma unroll
    for (int oc = 0; oc < C_DIM; ++oc)
      w2r[c4][oc] = *(const f32x4*)&bw2[oc * H_DIM + col];
  }

  const long wrow0 = ((long)blockIdx.x * 4 + wave) * 8;   // grid = BATCH/32
#pragma unroll 1
  for (int r = 0; r < 8; ++r) {
    const long row = wrow0 + r;
    const float* hr = H + row * H_DIM;
    f32x4 h[4];
#pragma unroll
    for (int c4 = 0; c4 < 4; ++c4) h[c4] = *(const f32x4*)&hr[c4 * 256 + lane * 4];
    float p[C_DIM] = {};
#pragma unroll
    for (int c4 = 0; c4 < 4; ++c4) {
      f32x4 a;
#pragma unroll
      for (int i = 0; i < 4; ++i) {
        const float hv = h[c4][i] * csr[c4][i] + tsr[c4][i];
        a[i] = (hv > 0.f) ? 1.f : ((hv < 0.f) ? -1.f : 0.f);   // jnp.sign semantics
      }
#pragma unroll
      for (int oc = 0; oc < C_DIM; ++oc) {
        const f32x4 wv = w2r[c4][oc];
        p[oc] += a[0] * wv[0] + a[1] * wv[1] + a[2] * wv[2] + a[3] * wv[3];
      }
    }
#pragma unroll
    for (int oc = 0; oc < C_DIM; ++oc) {
#pragma unroll
      for (int off = 32; off > 0; off >>= 1) p[oc] += __shfl_xor(p[oc], off, 64);
    }
    if (lane == 0) {
#pragma unroll
      for (int oc = 0; oc < C_DIM; ++oc) out[row * C_DIM + oc] = p[oc];
    }
  }
}

// ---------------------------------------------------------------------------
extern "C" void kernel_launch(void* const* d_in, const int* in_sizes, int n_in,
                              void* d_out, int out_size, void* d_ws, size_t ws_size,
                              hipStream_t stream) {
  const float* x     = (const float*)d_in[0];
  const float* w1    = (const float*)d_in[1];
  const float* w2    = (const float*)d_in[2];
  const float* gamma = (const float*)d_in[3];
  const float* beta  = (const float*)d_in[4];
  float* out = (float*)d_out;

  // workspace layout (bytes), all 256B-aligned offsets; total ~481.5 MB
  char* ws = (char*)d_ws;
  _Float16* X2     = (_Float16*)(ws + 0);            // 65536*1600*2 = 209,715,200
  float*    H      = (float*)  (ws + 209715200LL);   // 65536*1024*4 = 268,435,456
  _Float16* S2     = (_Float16*)(ws + 478150656LL);  // 1024*1600*2  =   3,276,800
  float*    BW2    = (float*)  (ws + 481427456LL);   // 10*1024*4    =      40,960
  float*    ALPHA1 = (float*)  (ws + 481468416LL);   // 1024*4       =       4,096
  float*    COLS   = (float*)  (ws + 481472512LL);   // 1024*4
  float*    COLQ   = (float*)  (ws + 481476608LL);   // 1024*4 (contiguous w/ COLS)

  hipMemsetAsync(COLS, 0, 2 * H_DIM * sizeof(float), stream);  // ws is poisoned each call
  split_x<<<(BATCH * 200) / 256, 256, 0, stream>>>(x, X2);
  prep_w<<<H_DIM + C_DIM, 256, 0, stream>>>(w1, w2, ALPHA1, S2, BW2);
  gemm1<<<1024, 512, 0, stream>>>(X2, S2, ALPHA1, H, COLS, COLQ);
  final_k<<<BATCH / 32, 256, 0, stream>>>(H, COLS, COLQ, gamma, beta, BW2, out);
}

// Round 4
// 606.472 us; speedup vs baseline: 1.1648x; 1.0141x over previous
//
#include <hip/hip_runtime.h>
#include <hip/hip_fp16.h>

#define BATCH   65536
#define IN_DIM  784
#define KPAD    800      // padded K per half (hi or lo)
#define K2      1600     // X2 row stride = [hi 800 | lo 800]
#define KH      800      // GEMM K per half (shared-B formulation)
#define NSTEP   25       // KH / 32
#define H_DIM   1024
#define C_DIM   10
#define BN_EPS  1e-5f

typedef _Float16 half8 __attribute__((ext_vector_type(8)));
typedef _Float16 half4 __attribute__((ext_vector_type(4)));
typedef float    f32x4 __attribute__((ext_vector_type(4)));

#if defined(__has_builtin)
#if __has_builtin(__builtin_amdgcn_global_load_lds)
#define HAVE_ASYNC 1
#endif
#endif
#ifndef HAVE_ASYNC
#define HAVE_ASYNC 0
#endif

// Stage 16B/lane from global into LDS. Async path: wave-uniform LDS base,
// HW scatters lane i -> base + i*16 (layout contiguous in lane order).
__device__ __forceinline__ void stage16(const _Float16* g, _Float16* ldsBase, int lane) {
#if HAVE_ASYNC
  __builtin_amdgcn_global_load_lds((const __attribute__((address_space(1))) void*)g,
                                   (__attribute__((address_space(3))) void*)ldsBase,
                                   16, 0, 0);
#else
  *(half8*)(ldsBase + lane * 8) = *(const half8*)g;
#endif
}

// ---------------------------------------------------------------------------
// K1: split x (fp32) into fp16 hi/lo halves, K-concatenated:
//     X2[b] = [hi(784) 0pad | lo(784) 0pad]
// R7: half8 (16B) stores, 100 threads/row (8 elems each).
// ---------------------------------------------------------------------------
__global__ __launch_bounds__(256) void split_x(const float* __restrict__ x,
                                               _Float16* __restrict__ X2) {
  const long tid = (long)blockIdx.x * 256 + threadIdx.x;   // BATCH*100 threads
  const long row = tid / 100;
  const int  q   = (int)(tid - row * 100);
  const int  k   = q * 8;
  half8 hi = {}, lo = {};
  if (k < IN_DIM) {                       // 784 = 8*98, exact
#pragma unroll
    for (int h4 = 0; h4 < 2; ++h4) {
      const f32x4 v = *(const f32x4*)&x[row * IN_DIM + k + h4 * 4];
#pragma unroll
      for (int i = 0; i < 4; ++i) {
        const _Float16 h = (_Float16)v[i];
        hi[h4 * 4 + i] = h;
        lo[h4 * 4 + i] = (_Float16)(v[i] - (float)h);
      }
    }
  }
  _Float16* dst = X2 + row * K2 + k;
  *(half8*)dst = hi;
  *(half8*)(dst + KPAD) = lo;
}

// ---------------------------------------------------------------------------
// K2: weight prep. Blocks 0..1023: alpha1[j]=mean|w1[j]|, S2[j]=sign fp16 [KH wide].
//     Blocks 1024..1033: bw2[c][j] = mean|w2[c]| * sign(w2[c][j]) fp32.
// R7: S2 is 800-wide (no hi/lo duplication — shared-B GEMM).
// ---------------------------------------------------------------------------
__global__ __launch_bounds__(256) void prep_w(const float* __restrict__ w1,
                                              const float* __restrict__ w2,
                                              float* __restrict__ alpha1,
                                              _Float16* __restrict__ S2,
                                              float* __restrict__ bw2) {
  __shared__ float red[4];
  const int tid = threadIdx.x, lane = tid & 63, wave = tid >> 6;
  const int j = blockIdx.x;
  if (j < H_DIM) {
    const float* wr = w1 + (long)j * IN_DIM;
    float s = 0.f;
    for (int k = tid; k < IN_DIM; k += 256) s += fabsf(wr[k]);
#pragma unroll
    for (int off = 32; off > 0; off >>= 1) s += __shfl_xor(s, off, 64);
    if (lane == 0) red[wave] = s;
    __syncthreads();
    if (tid == 0) alpha1[j] = (red[0] + red[1] + red[2] + red[3]) * (1.f / IN_DIM);
    _Float16* dr = S2 + (long)j * KH;
    for (int k = tid; k < KH; k += 256) {
      const float v = (k < IN_DIM) ? wr[k] : 0.f;
      dr[k] = (_Float16)((v > 0.f) ? 1.f : ((v < 0.f) ? -1.f : 0.f));
    }
  } else {
    const int c = j - H_DIM;
    const float* wr = w2 + (long)c * H_DIM;
    float s = 0.f;
    for (int k = tid; k < H_DIM; k += 256) s += fabsf(wr[k]);
#pragma unroll
    for (int off = 32; off > 0; off >>= 1) s += __shfl_xor(s, off, 64);
    if (lane == 0) red[wave] = s;
    __syncthreads();
    const float alpha = (red[0] + red[1] + red[2] + red[3]) * (1.f / H_DIM);
    for (int k = tid; k < H_DIM; k += 256) {
      const float v = wr[k];
      const float sg = (v > 0.f) ? 1.f : ((v < 0.f) ? -1.f : 0.f);
      bw2[(long)c * H_DIM + k] = alpha * sg;
    }
  }
}

// ---------------------------------------------------------------------------
// K3: GEMM1  H[b][j] = alpha1[j]*sum_k(Xhi[b][k]+... ) shared-B formulation:
//     acc = Xhi_tile @ B + Xlo_tile @ B accumulated per 32-K step, K=800.
//
// R7: 256x256 tile, 8 waves, BK=32, 3-slot LDS ring of {Ahi|Alo|B} 48KB each
// (144 KiB total). R6 null result (depth 4->5 = no change) showed we are
// throughput-bound on staging bytes + LDS traffic, not latency-bound ->
// this cuts staged bytes 25% (B staged once for both halves), LDS frag
// reads/FLOP 17%, barriers 2x (25 steps vs 50 tiles).
//  - lead-2 prefetch, 6 loads/thread/step, counted vmcnt(6) at step top
//    (retires exactly step t's loads; step t+1's stay in flight).
//  - phase a: stage Ahi/Alo(t+2), read B+Ahi frags, 32 MFMA (hi).
//    phase b: stage B(t+2), read Alo frags (B reused in regs), 32 MFMA (lo).
//  - Safety: slot (t+2)%3 == (t-1)%3 fully read during step t-1, before all
//    waves reach top-of-t barrier; stages issued after it -> no race.
//  - drain vmcnt(0) after loop (LDS-DMA must not outlive the block).
//  - swizzle (verified R2, conflict=0): source chunk (lane&3)^((lane>>3)&3),
//    read chunk kc^((fr>>1)&3); LDS linear for global_load_lds.
//  - XCD remap: 1024 blocks, b%8=XCD, n-tile fastest within XCD.
// ---------------------------------------------------------------------------
__global__ __launch_bounds__(512, 2) void gemm1(const _Float16* __restrict__ X2,
                                                const _Float16* __restrict__ S2,
                                                const float* __restrict__ alpha1,
                                                float* __restrict__ H,
                                                float* __restrict__ colsum,
                                                float* __restrict__ colsumsq) {
  __shared__ _Float16 lds[3 * 24576];   // slot: Ahi[256x32] | Alo[256x32] | B[256x32]
  const int tid  = threadIdx.x;
  const int lane = tid & 63;
  const int w    = tid >> 6;            // wave 0..7
  const int wr   = w >> 2;              // 0..1  (M dir, 128 rows each)
  const int wc   = w & 3;               // 0..3  (N dir, 64 cols each)

  // XCD-aware remap: 1024 blocks -> (mt 0..255, nt 0..3), nt fastest per XCD.
  const int b     = blockIdx.x;
  const int xcd   = b & 7;
  const int local = b >> 3;                       // 0..127
  const long m0   = (long)(xcd * 32 + (local >> 2)) * 256;
  const int  n0   = (local & 3) * 256;

  // staging: swizzled global source chunk per lane, linear LDS dest
  const int c8 = ((lane & 3) ^ ((lane >> 3) & 3)) * 8;
  const _Float16* aG = X2 + (m0 + w * 32 + (lane >> 2)) * K2 + c8;       // hi; lo at +KPAD
  const _Float16* bG = S2 + (long)(n0 + w * 32 + (lane >> 2)) * KH + c8; // S2 800-wide
  const int ldsW0 = (w * 32) * 32;                // wave's staging rows (halves)
  const int ldsW1 = (w * 32 + 16) * 32;

  // read-side frag offsets (same swizzle family, verified conflict-free)
  const int fr = lane & 15;                       // n (B) / m (A) within 16
  const int kc = lane >> 4;                       // K 16B-chunk index
  const int cp = (kc ^ ((fr >> 1) & 3)) * 8;
  const int aoff = (wr * 128 + fr) * 32 + cp;     // + mi*512
  const int boff = (wc * 64 + fr) * 32 + cp;      // + ni*512

  f32x4 acc[8][4] = {};

  // prologue: stage steps 0,1 (12 loads/thread in flight)
#pragma unroll
  for (int kt = 0; kt < 2; ++kt) {
    _Float16* S = &lds[kt * 24576];
    const int k0 = kt * 32;
    stage16(aG + k0,                  S + ldsW0, lane);
    stage16(aG + 16 * K2 + k0,        S + ldsW1, lane);
    stage16(aG + KPAD + k0,           S + 8192 + ldsW0, lane);
    stage16(aG + KPAD + 16 * K2 + k0, S + 8192 + ldsW1, lane);
    stage16(bG + k0,                  S + 16384 + ldsW0, lane);
    stage16(bG + 16 * KH + k0,        S + 16384 + ldsW1, lane);
  }

  int scur = 0;   // slot holding step t
  int spre = 2;   // slot receiving step t+2
  for (int t = 0; t < NSTEP; ++t) {
    _Float16* S = &lds[scur * 24576];
    const int ks = (t + 2 < NSTEP) ? (t + 2) * 32 : (NSTEP - 1) * 32;  // clamp: uniform counts
    _Float16* P = &lds[spre * 24576];

    // step boundary: step t landed for all waves; step t+1 stays in flight
    asm volatile("s_waitcnt vmcnt(6)" ::: "memory");
    __builtin_amdgcn_s_barrier();
    asm volatile("" ::: "memory");   // keep frag loads below the barrier

    // ---- phase a (hi): issue A-stages of t+2 first, then frags, then MFMA
    stage16(aG + ks,                  P + ldsW0, lane);
    stage16(aG + 16 * K2 + ks,        P + ldsW1, lane);
    stage16(aG + KPAD + ks,           P + 8192 + ldsW0, lane);
    stage16(aG + KPAD + 16 * K2 + ks, P + 8192 + ldsW1, lane);
    half8 af[8], bf[4];
#pragma unroll
    for (int ni = 0; ni < 4; ++ni) bf[ni] = *(const half8*)&S[16384 + boff + ni * 512];
#pragma unroll
    for (int mi = 0; mi < 8; ++mi) af[mi] = *(const half8*)&S[aoff + mi * 512];
    __builtin_amdgcn_s_setprio(1);
#pragma unroll
    for (int mi = 0; mi < 8; ++mi)
#pragma unroll
      for (int ni = 0; ni < 4; ++ni)
        acc[mi][ni] = __builtin_amdgcn_mfma_f32_16x16x32_f16(af[mi], bf[ni], acc[mi][ni], 0, 0, 0);
    __builtin_amdgcn_s_setprio(0);
    __builtin_amdgcn_s_barrier();

    // ---- phase b (lo): issue B-stage of t+2, read Alo frags, B reused in regs
    stage16(bG + ks,           P + 16384 + ldsW0, lane);
    stage16(bG + 16 * KH + ks, P + 16384 + ldsW1, lane);
#pragma unroll
    for (int mi = 0; mi < 8; ++mi) af[mi] = *(const half8*)&S[8192 + aoff + mi * 512];
    __builtin_amdgcn_s_setprio(1);
#pragma unroll
    for (int mi = 0; mi < 8; ++mi)
#pragma unroll
      for (int ni = 0; ni < 4; ++ni)
        acc[mi][ni] = __builtin_amdgcn_mfma_f32_16x16x32_f16(af[mi], bf[ni], acc[mi][ni], 0, 0, 0);
    __builtin_amdgcn_s_setprio(0);

    scur = (scur == 2) ? 0 : scur + 1;
    spre = (spre == 2) ? 0 : spre + 1;
  }

  // Drain in-flight LDS-DMA before epilogue/endpgm: late DMA landing after LDS
  // is reassigned to a new workgroup would corrupt that block's tiles.
  asm volatile("s_waitcnt vmcnt(0)" ::: "memory");

  // epilogue: D layout col=lane&15, row=(lane>>4)*4+r  [measured m89/m91]
  // + fused column sum/sumsq
  const int rq = (lane >> 4) * 4;
#pragma unroll
  for (int ni = 0; ni < 4; ++ni) {
    const int col = n0 + wc * 64 + ni * 16 + fr;
    const float a1 = alpha1[col];
    float s = 0.f, q = 0.f;
#pragma unroll
    for (int mi = 0; mi < 8; ++mi) {
#pragma unroll
      for (int r = 0; r < 4; ++r) {
        const long row = m0 + wr * 128 + mi * 16 + rq + r;
        const float v = acc[mi][ni][r] * a1;
        H[row * H_DIM + col] = v;
        s += v;
        q += v * v;
      }
    }
    s += __shfl_xor(s, 16, 64);
    s += __shfl_xor(s, 32, 64);
    q += __shfl_xor(q, 16, 64);
    q += __shfl_xor(q, 32, 64);
    if ((lane >> 4) == 0) {
      atomicAdd(&colsum[col], s);
      atomicAdd(&colsumsq[col], q);
    }
  }
}

// ---------------------------------------------------------------------------
// K5: normalize -> sign -> out = a @ bw2^T.
// Wave-per-row, w2/cs/ts fully in REGISTERS (statically indexed), no LDS,
// no syncthreads. Lane covers cols {c4*256+lane*4} -> H loads 1KB/wave
// fully-coalesced. launch_bounds(256,2) -> 8 waves/CU.
// ---------------------------------------------------------------------------
__global__ __launch_bounds__(256, 2) void final_k(const float* __restrict__ H,
                                                  const float* __restrict__ colsum,
                                                  const float* __restrict__ colsumsq,
                                                  const float* __restrict__ gamma,
                                                  const float* __restrict__ beta,
                                                  const float* __restrict__ bw2,
                                                  float* __restrict__ out) {
  const int tid = threadIdx.x, lane = tid & 63, wave = tid >> 6;
  f32x4 w2r[4][C_DIM];
  f32x4 csr[4], tsr[4];
#pragma unroll
  for (int c4 = 0; c4 < 4; ++c4) {
    const int col = c4 * 256 + lane * 4;
    const f32x4 s  = *(const f32x4*)&colsum[col];
    const f32x4 q  = *(const f32x4*)&colsumsq[col];
    const f32x4 g  = *(const f32x4*)&gamma[col];
    const f32x4 bt = *(const f32x4*)&beta[col];
    f32x4 c, t;
#pragma unroll
    for (int i = 0; i < 4; ++i) {
      const float mu  = s[i] * (1.f / BATCH);
      const float var = q[i] * (1.f / BATCH) - mu * mu;  // biased var
      c[i] = g[i] * rsqrtf(var + BN_EPS);
      t[i] = bt[i] - c[i] * mu;        // sign(gamma*(h-mu)*invstd+beta) = sign(c*h+t)
    }
    csr[c4] = c;
    tsr[c4] = t;
#pragma unroll
    for (int oc = 0; oc < C_DIM; ++oc)
      w2r[c4][oc] = *(const f32x4*)&bw2[oc * H_DIM + col];
  }

  const long wrow0 = ((long)blockIdx.x * 4 + wave) * 8;   // grid = BATCH/32
#pragma unroll 1
  for (int r = 0; r < 8; ++r) {
    const long row = wrow0 + r;
    const float* hr = H + row * H_DIM;
    f32x4 h[4];
#pragma unroll
    for (int c4 = 0; c4 < 4; ++c4) h[c4] = *(const f32x4*)&hr[c4 * 256 + lane * 4];
    float p[C_DIM] = {};
#pragma unroll
    for (int c4 = 0; c4 < 4; ++c4) {
      f32x4 a;
#pragma unroll
      for (int i = 0; i < 4; ++i) {
        const float hv = h[c4][i] * csr[c4][i] + tsr[c4][i];
        a[i] = (hv > 0.f) ? 1.f : ((hv < 0.f) ? -1.f : 0.f);   // jnp.sign semantics
      }
#pragma unroll
      for (int oc = 0; oc < C_DIM; ++oc) {
        const f32x4 wv = w2r[c4][oc];
        p[oc] += a[0] * wv[0] + a[1] * wv[1] + a[2] * wv[2] + a[3] * wv[3];
      }
    }
#pragma unroll
    for (int oc = 0; oc < C_DIM; ++oc) {
#pragma unroll
      for (int off = 32; off > 0; off >>= 1) p[oc] += __shfl_xor(p[oc], off, 64);
    }
    if (lane == 0) {
#pragma unroll
      for (int oc = 0; oc < C_DIM; ++oc) out[row * C_DIM + oc] = p[oc];
    }
  }
}

// ---------------------------------------------------------------------------
extern "C" void kernel_launch(void* const* d_in, const int* in_sizes, int n_in,
                              void* d_out, int out_size, void* d_ws, size_t ws_size,
                              hipStream_t stream) {
  const float* x     = (const float*)d_in[0];
  const float* w1    = (const float*)d_in[1];
  const float* w2    = (const float*)d_in[2];
  const float* gamma = (const float*)d_in[3];
  const float* beta  = (const float*)d_in[4];
  float* out = (float*)d_out;

  // workspace layout (bytes), all 256B-aligned offsets; total ~480 MB
  char* ws = (char*)d_ws;
  _Float16* X2     = (_Float16*)(ws + 0);            // 65536*1600*2 = 209,715,200
  float*    H      = (float*)  (ws + 209715200LL);   // 65536*1024*4 = 268,435,456
  _Float16* S2     = (_Float16*)(ws + 478150656LL);  // 1024*800*2   =   1,638,400
  float*    BW2    = (float*)  (ws + 481427456LL);   // 10*1024*4    =      40,960
  float*    ALPHA1 = (float*)  (ws + 481468416LL);   // 1024*4       =       4,096
  float*    COLS   = (float*)  (ws + 481472512LL);   // 1024*4
  float*    COLQ   = (float*)  (ws + 481476608LL);   // 1024*4 (contiguous w/ COLS)

  hipMemsetAsync(COLS, 0, 2 * H_DIM * sizeof(float), stream);  // ws is poisoned each call
  split_x<<<(BATCH * 100) / 256, 256, 0, stream>>>(x, X2);
  prep_w<<<H_DIM + C_DIM, 256, 0, stream>>>(w1, w2, ALPHA1, S2, BW2);
  gemm1<<<1024, 512, 0, stream>>>(X2, S2, ALPHA1, H, COLS, COLQ);
  final_k<<<BATCH / 32, 256, 0, stream>>>(H, COLS, COLQ, gamma, beta, BW2, out);
}

// Round 5
// 586.190 us; speedup vs baseline: 1.2051x; 1.0346x over previous
//
#include <hip/hip_runtime.h>
#include <hip/hip_fp16.h>

#define BATCH   65536
#define IN_DIM  784
#define KH      800      // GEMM K per half (shared-B formulation); S2 is KH wide
#define NSTEP   25       // KH / 32
#define H_DIM   1024
#define C_DIM   10
#define BN_EPS  1e-5f
#define SLOT    24576    // halves per LDS slot: Ahi 8192 | Alo 8192 | B 8192 (48 KB)

typedef _Float16 half8 __attribute__((ext_vector_type(8)));
typedef float    f32x4 __attribute__((ext_vector_type(4)));

#if defined(__has_builtin)
#if __has_builtin(__builtin_amdgcn_global_load_lds)
#define HAVE_ASYNC 1
#endif
#endif
#ifndef HAVE_ASYNC
#define HAVE_ASYNC 0
#endif

// Stage 16B/lane from global into LDS (wave-uniform LDS base; HW scatters
// lane i -> base + i*16). Used for B only; A is reg-staged from x.
__device__ __forceinline__ void stage16(const _Float16* g, _Float16* ldsBase, int lane) {
#if HAVE_ASYNC
  __builtin_amdgcn_global_load_lds((const __attribute__((address_space(1))) void*)g,
                                   (__attribute__((address_space(3))) void*)ldsBase,
                                   16, 0, 0);
#else
  *(half8*)(ldsBase + lane * 8) = *(const half8*)g;
#endif
}

// ---------------------------------------------------------------------------
// K2: weight prep. Blocks 0..1023: alpha1[j]=mean|w1[j]|, S2[j]=sign fp16 [KH].
//     Blocks 1024..1033: bw2[c][j] = mean|w2[c]| * sign(w2[c][j]) fp32.
//     Block 1034: zero colsum/colsumsq (replaces the hipMemsetAsync node).
// ---------------------------------------------------------------------------
__global__ __launch_bounds__(256) void prep_w(const float* __restrict__ w1,
                                              const float* __restrict__ w2,
                                              float* __restrict__ alpha1,
                                              _Float16* __restrict__ S2,
                                              float* __restrict__ bw2,
                                              float* __restrict__ colz) {
  __shared__ float red[4];
  const int tid = threadIdx.x, lane = tid & 63, wave = tid >> 6;
  const int j = blockIdx.x;
  if (j < H_DIM) {
    const float* wr = w1 + (long)j * IN_DIM;
    float s = 0.f;
    for (int k = tid; k < IN_DIM; k += 256) s += fabsf(wr[k]);
#pragma unroll
    for (int off = 32; off > 0; off >>= 1) s += __shfl_xor(s, off, 64);
    if (lane == 0) red[wave] = s;
    __syncthreads();
    if (tid == 0) alpha1[j] = (red[0] + red[1] + red[2] + red[3]) * (1.f / IN_DIM);
    _Float16* dr = S2 + (long)j * KH;
    for (int k = tid; k < KH; k += 256) {
      const float v = (k < IN_DIM) ? wr[k] : 0.f;
      dr[k] = (_Float16)((v > 0.f) ? 1.f : ((v < 0.f) ? -1.f : 0.f));
    }
  } else if (j < H_DIM + C_DIM) {
    const int c = j - H_DIM;
    const float* wr = w2 + (long)c * H_DIM;
    float s = 0.f;
    for (int k = tid; k < H_DIM; k += 256) s += fabsf(wr[k]);
#pragma unroll
    for (int off = 32; off > 0; off >>= 1) s += __shfl_xor(s, off, 64);
    if (lane == 0) red[wave] = s;
    __syncthreads();
    const float alpha = (red[0] + red[1] + red[2] + red[3]) * (1.f / H_DIM);
    for (int k = tid; k < H_DIM; k += 256) {
      const float v = wr[k];
      const float sg = (v > 0.f) ? 1.f : ((v < 0.f) ? -1.f : 0.f);
      bw2[(long)c * H_DIM + k] = alpha * sg;
    }
  } else {
    for (int k = tid; k < 2 * H_DIM; k += 256) colz[k] = 0.f;  // ws poisoned each call
  }
}

// ---------------------------------------------------------------------------
// K3: GEMM1  H[b][j] = alpha1[j]*(Xhi@B + Xlo@B),  M=65536, N=1024, K=800x2.
//
// R8 (= R7 + split_x FUSED): A is staged from x (f32) directly — per step each
// thread loads 64B of x, converts hi/lo f16 in-register (same RTN cast as the
// old split_x => bit-identical), ds_write_b128 into the SAME swizzled layout.
// Eliminates the split_x kernel and X2 (210MB written + re-read) entirely.
//  - A write layout: LDS[row][chunk c] holds global chunk c ^ ((row>>1)&3) —
//    exact inverse of the read swizzle (verified R2, conflict=0). Write bank
//    pattern: each b128 write instr covers all 32 banks exactly twice = min
//    cycles (balanced; derivation in session notes).
//  - Thread map: row = tid>>1 (0..255), half = tid&1 (16 f32 each). Pad cols
//    784..799: guard loads, write zero (B rows there are zero too, but LDS
//    garbage could be NaN -> must zero).
//  - Sync unchanged: 2 barriers/step; writes to slot t+2 issued after top-of-t
//    barrier; readers' lgkmcnt precedes their MFMAs precedes barrier arrival;
//    A-load vmcnt waits (compiler) retire earlier B-DMAs in-order, so the
//    explicit vmcnt(2) at step top is usually already satisfied.
//  - B staging via global_load_lds as before; drain vmcnt(0) after loop.
// ---------------------------------------------------------------------------
__global__ __launch_bounds__(512) void gemm1(const float* __restrict__ x,
                                             const _Float16* __restrict__ S2,
                                             const float* __restrict__ alpha1,
                                             float* __restrict__ H,
                                             float* __restrict__ colsum,
                                             float* __restrict__ colsumsq) {
  __shared__ _Float16 lds[3 * SLOT];   // 3 slots x {Ahi|Alo|B} = 144 KiB
  const int tid  = threadIdx.x;
  const int lane = tid & 63;
  const int w    = tid >> 6;            // wave 0..7
  const int wr   = w >> 2;              // 0..1  (M dir, 128 rows each)
  const int wc   = w & 3;               // 0..3  (N dir, 64 cols each)

  // XCD-aware remap: 1024 blocks -> (mt 0..255, nt 0..3), nt fastest per XCD.
  const int b     = blockIdx.x;
  const int xcd   = b & 7;
  const int local = b >> 3;                       // 0..127
  const long m0   = (long)(xcd * 32 + (local >> 2)) * 256;
  const int  n0   = (local & 3) * 256;

  // ---- A staging (reg-staged from x): thread -> (row, half)
  const int rowS  = tid >> 1;                     // 0..255 within tile
  const int halfS = tid & 1;                      // 16 f32 each
  const float* xp = x + (m0 + rowS) * (long)IN_DIM;
  const int sA = (rowS >> 1) & 3;                 // write-side swizzle
  const int c0 = (halfS * 2) ^ sA;
  const int c1 = (halfS * 2 + 1) ^ sA;
  const int aw = rowS * 32;                       // halves base within Ahi

  // ---- B staging (DMA): swizzled global source chunk, linear LDS dest
  const int c8 = ((lane & 3) ^ ((lane >> 3) & 3)) * 8;
  const _Float16* bG = S2 + (long)(n0 + w * 32 + (lane >> 2)) * KH + c8;
  const int ldsW0 = (w * 32) * 32;
  const int ldsW1 = (w * 32 + 16) * 32;

  // ---- read-side frag offsets (same swizzle family, verified conflict-free)
  const int fr = lane & 15;
  const int kc = lane >> 4;
  const int cp = (kc ^ ((fr >> 1) & 3)) * 8;
  const int aoff = (wr * 128 + fr) * 32 + cp;     // + mi*512
  const int boff = (wc * 64 + fr) * 32 + cp;      // + ni*512

  f32x4 acc[8][4] = {};

  // prologue: stage steps 0,1 (A reg-staged+written, B DMA'd)
#pragma unroll
  for (int kt = 0; kt < 2; ++kt) {
    _Float16* S = &lds[kt * SLOT];
    const int ks = kt * 32;
    const bool valid = (ks + halfS * 16) <= (IN_DIM - 16);
    half8 hh0 = {}, hh1 = {}, hl0 = {}, hl1 = {};
    if (valid) {
      const float* src = xp + ks + halfS * 16;
      f32x4 v0 = *(const f32x4*)(src);
      f32x4 v1 = *(const f32x4*)(src + 4);
      f32x4 v2 = *(const f32x4*)(src + 8);
      f32x4 v3 = *(const f32x4*)(src + 12);
#pragma unroll
      for (int i = 0; i < 8; ++i) {
        const float f0 = (i < 4) ? v0[i & 3] : v1[i & 3];
        const float f1 = (i < 4) ? v2[i & 3] : v3[i & 3];
        const _Float16 h0 = (_Float16)f0, h1 = (_Float16)f1;
        hh0[i] = h0; hl0[i] = (_Float16)(f0 - (float)h0);
        hh1[i] = h1; hl1[i] = (_Float16)(f1 - (float)h1);
      }
    }
    *(half8*)(S + aw + c0 * 8) = hh0;
    *(half8*)(S + aw + c1 * 8) = hh1;
    *(half8*)(S + 8192 + aw + c0 * 8) = hl0;
    *(half8*)(S + 8192 + aw + c1 * 8) = hl1;
    stage16(bG + ks,           S + 16384 + ldsW0, lane);
    stage16(bG + 16 * KH + ks, S + 16384 + ldsW1, lane);
  }
  asm volatile("s_waitcnt vmcnt(2) lgkmcnt(0)" ::: "memory");

  int scur = 0;   // slot holding step t
  int spre = 2;   // slot receiving step t+2
  for (int t = 0; t < NSTEP; ++t) {
    _Float16* S = &lds[scur * SLOT];
    _Float16* P = &lds[spre * SLOT];
    const int tcl = (t + 2 < NSTEP) ? (t + 2) : (NSTEP - 1);  // clamp: uniform counts
    const int ks = tcl * 32;
    const bool validP = (ks + halfS * 16) <= (IN_DIM - 16);

    // step boundary: step t landed for all waves (B(t) retired in-order by
    // earlier A-load waits; writes drained by readers' lgkm before barrier)
    asm volatile("" ::: "memory");
    asm volatile("s_waitcnt vmcnt(2)" ::: "memory");
    __builtin_amdgcn_s_barrier();
    asm volatile("" ::: "memory");

    // ---- phase a (hi): issue A-loads for step t+2, frags, 32 MFMA
    f32x4 v0, v1, v2, v3;
    if (validP) {
      const float* src = xp + ks + halfS * 16;
      v0 = *(const f32x4*)(src);
      v1 = *(const f32x4*)(src + 4);
      v2 = *(const f32x4*)(src + 8);
      v3 = *(const f32x4*)(src + 12);
    }
    half8 af[8], bf[4];
#pragma unroll
    for (int ni = 0; ni < 4; ++ni) bf[ni] = *(const half8*)&S[16384 + boff + ni * 512];
#pragma unroll
    for (int mi = 0; mi < 8; ++mi) af[mi] = *(const half8*)&S[aoff + mi * 512];
    __builtin_amdgcn_s_setprio(1);
#pragma unroll
    for (int mi = 0; mi < 8; ++mi)
#pragma unroll
      for (int ni = 0; ni < 4; ++ni)
        acc[mi][ni] = __builtin_amdgcn_mfma_f32_16x16x32_f16(af[mi], bf[ni], acc[mi][ni], 0, 0, 0);
    __builtin_amdgcn_s_setprio(0);
    asm volatile("" ::: "memory");
    __builtin_amdgcn_s_barrier();
    asm volatile("" ::: "memory");

    // ---- phase b (lo): convert+write A(t+2), B-DMA(t+2), Alo frags, 32 MFMA
    {
      half8 hh0 = {}, hh1 = {}, hl0 = {}, hl1 = {};
      if (validP) {
#pragma unroll
        for (int i = 0; i < 8; ++i) {
          const float f0 = (i < 4) ? v0[i & 3] : v1[i & 3];
          const float f1 = (i < 4) ? v2[i & 3] : v3[i & 3];
          const _Float16 h0 = (_Float16)f0, h1 = (_Float16)f1;
          hh0[i] = h0; hl0[i] = (_Float16)(f0 - (float)h0);
          hh1[i] = h1; hl1[i] = (_Float16)(f1 - (float)h1);
        }
      }
      *(half8*)(P + aw + c0 * 8) = hh0;
      *(half8*)(P + aw + c1 * 8) = hh1;
      *(half8*)(P + 8192 + aw + c0 * 8) = hl0;
      *(half8*)(P + 8192 + aw + c1 * 8) = hl1;
    }
    stage16(bG + ks,           P + 16384 + ldsW0, lane);
    stage16(bG + 16 * KH + ks, P + 16384 + ldsW1, lane);
#pragma unroll
    for (int mi = 0; mi < 8; ++mi) af[mi] = *(const half8*)&S[8192 + aoff + mi * 512];
    __builtin_amdgcn_s_setprio(1);
#pragma unroll
    for (int mi = 0; mi < 8; ++mi)
#pragma unroll
      for (int ni = 0; ni < 4; ++ni)
        acc[mi][ni] = __builtin_amdgcn_mfma_f32_16x16x32_f16(af[mi], bf[ni], acc[mi][ni], 0, 0, 0);
    __builtin_amdgcn_s_setprio(0);

    scur = (scur == 2) ? 0 : scur + 1;
    spre = (spre == 2) ? 0 : spre + 1;
  }

  // Drain in-flight LDS-DMA before epilogue/endpgm (LDS may be reassigned).
  asm volatile("s_waitcnt vmcnt(0)" ::: "memory");

  // epilogue: D layout col=lane&15, row=(lane>>4)*4+r  [measured m89/m91]
  // + fused column sum/sumsq
  const int rq = (lane >> 4) * 4;
#pragma unroll
  for (int ni = 0; ni < 4; ++ni) {
    const int col = n0 + wc * 64 + ni * 16 + fr;
    const float a1 = alpha1[col];
    float s = 0.f, q = 0.f;
#pragma unroll
    for (int mi = 0; mi < 8; ++mi) {
#pragma unroll
      for (int r = 0; r < 4; ++r) {
        const long row = m0 + wr * 128 + mi * 16 + rq + r;
        const float v = acc[mi][ni][r] * a1;
        H[row * H_DIM + col] = v;
        s += v;
        q += v * v;
      }
    }
    s += __shfl_xor(s, 16, 64);
    s += __shfl_xor(s, 32, 64);
    q += __shfl_xor(q, 16, 64);
    q += __shfl_xor(q, 32, 64);
    if ((lane >> 4) == 0) {
      atomicAdd(&colsum[col], s);
      atomicAdd(&colsumsq[col], q);
    }
  }
}

// ---------------------------------------------------------------------------
// K5: normalize -> sign -> out = a @ bw2^T.
// Wave-per-row, w2/cs/ts fully in REGISTERS (statically indexed), no LDS,
// no syncthreads. Lane covers cols {c4*256+lane*4} -> H loads 1KB/wave
// fully-coalesced. launch_bounds(256,2) -> 8 waves/CU.
// ---------------------------------------------------------------------------
__global__ __launch_bounds__(256, 2) void final_k(const float* __restrict__ H,
                                                  const float* __restrict__ colsum,
                                                  const float* __restrict__ colsumsq,
                                                  const float* __restrict__ gamma,
                                                  const float* __restrict__ beta,
                                                  const float* __restrict__ bw2,
                                                  float* __restrict__ out) {
  const int tid = threadIdx.x, lane = tid & 63, wave = tid >> 6;
  f32x4 w2r[4][C_DIM];
  f32x4 csr[4], tsr[4];
#pragma unroll
  for (int c4 = 0; c4 < 4; ++c4) {
    const int col = c4 * 256 + lane * 4;
    const f32x4 s  = *(const f32x4*)&colsum[col];
    const f32x4 q  = *(const f32x4*)&colsumsq[col];
    const f32x4 g  = *(const f32x4*)&gamma[col];
    const f32x4 bt = *(const f32x4*)&beta[col];
    f32x4 c, t;
#pragma unroll
    for (int i = 0; i < 4; ++i) {
      const float mu  = s[i] * (1.f / BATCH);
      const float var = q[i] * (1.f / BATCH) - mu * mu;  // biased var
      c[i] = g[i] * rsqrtf(var + BN_EPS);
      t[i] = bt[i] - c[i] * mu;        // sign(gamma*(h-mu)*invstd+beta) = sign(c*h+t)
    }
    csr[c4] = c;
    tsr[c4] = t;
#pragma unroll
    for (int oc = 0; oc < C_DIM; ++oc)
      w2r[c4][oc] = *(const f32x4*)&bw2[oc * H_DIM + col];
  }

  const long wrow0 = ((long)blockIdx.x * 4 + wave) * 8;   // grid = BATCH/32
#pragma unroll 1
  for (int r = 0; r < 8; ++r) {
    const long row = wrow0 + r;
    const float* hr = H + row * H_DIM;
    f32x4 h[4];
#pragma unroll
    for (int c4 = 0; c4 < 4; ++c4) h[c4] = *(const f32x4*)&hr[c4 * 256 + lane * 4];
    float p[C_DIM] = {};
#pragma unroll
    for (int c4 = 0; c4 < 4; ++c4) {
      f32x4 a;
#pragma unroll
      for (int i = 0; i < 4; ++i) {
        const float hv = h[c4][i] * csr[c4][i] + tsr[c4][i];
        a[i] = (hv > 0.f) ? 1.f : ((hv < 0.f) ? -1.f : 0.f);   // jnp.sign semantics
      }
#pragma unroll
      for (int oc = 0; oc < C_DIM; ++oc) {
        const f32x4 wv = w2r[c4][oc];
        p[oc] += a[0] * wv[0] + a[1] * wv[1] + a[2] * wv[2] + a[3] * wv[3];
      }
    }
#pragma unroll
    for (int oc = 0; oc < C_DIM; ++oc) {
#pragma unroll
      for (int off = 32; off > 0; off >>= 1) p[oc] += __shfl_xor(p[oc], off, 64);
    }
    if (lane == 0) {
#pragma unroll
      for (int oc = 0; oc < C_DIM; ++oc) out[row * C_DIM + oc] = p[oc];
    }
  }
}

// ---------------------------------------------------------------------------
extern "C" void kernel_launch(void* const* d_in, const int* in_sizes, int n_in,
                              void* d_out, int out_size, void* d_ws, size_t ws_size,
                              hipStream_t stream) {
  const float* x     = (const float*)d_in[0];
  const float* w1    = (const float*)d_in[1];
  const float* w2    = (const float*)d_in[2];
  const float* gamma = (const float*)d_in[3];
  const float* beta  = (const float*)d_in[4];
  float* out = (float*)d_out;

  // workspace layout (bytes), 256B-aligned offsets; total ~270.2 MB (X2 gone)
  char* ws = (char*)d_ws;
  float*    H      = (float*)  (ws + 0);             // 65536*1024*4 = 268,435,456
  _Float16* S2     = (_Float16*)(ws + 268435456LL);  // 1024*800*2   =   1,638,400
  float*    BW2    = (float*)  (ws + 270073856LL);   // 10*1024*4    =      40,960
  float*    ALPHA1 = (float*)  (ws + 270114816LL);   // 1024*4       =       4,096
  float*    COLS   = (float*)  (ws + 270118912LL);   // 1024*4
  float*    COLQ   = (float*)  (ws + 270123008LL);   // 1024*4 (contiguous w/ COLS)

  prep_w<<<H_DIM + C_DIM + 1, 256, 0, stream>>>(w1, w2, ALPHA1, S2, BW2, COLS);
  gemm1<<<1024, 512, 0, stream>>>(x, S2, ALPHA1, H, COLS, COLQ);
  final_k<<<BATCH / 32, 256, 0, stream>>>(H, COLS, COLQ, gamma, beta, BW2, out);
}

// Round 6
// 579.327 us; speedup vs baseline: 1.2194x; 1.0118x over previous
//
#include <hip/hip_runtime.h>
#include <hip/hip_fp16.h>

#define BATCH   65536
#define IN_DIM  784
#define KH      800      // GEMM K per half (shared-B); S2 is KH wide
#define NSTEP   25       // KH / 32
#define H_DIM   1024
#define C_DIM   10
#define BN_EPS  1e-5f
#define SLOT    24576    // halves per LDS slot: Ahi 8192 | Alo 8192 | B 8192 (48 KB)

typedef _Float16 half8 __attribute__((ext_vector_type(8)));
typedef float    f32x4 __attribute__((ext_vector_type(4)));

#if defined(__has_builtin)
#if __has_builtin(__builtin_amdgcn_global_load_lds)
#define HAVE_ASYNC 1
#endif
#endif
#ifndef HAVE_ASYNC
#define HAVE_ASYNC 0
#endif

__device__ __forceinline__ void stage16(const _Float16* g, _Float16* ldsBase, int lane) {
#if HAVE_ASYNC
  __builtin_amdgcn_global_load_lds((const __attribute__((address_space(1))) void*)g,
                                   (__attribute__((address_space(3))) void*)ldsBase,
                                   16, 0, 0);
#else
  *(half8*)(ldsBase + lane * 8) = *(const half8*)g;
#endif
}

// ---------------------------------------------------------------------------
// K2: weight prep.
//  blocks 0..1023:    alpha1[j]=mean|w1[j]|, S2[j]=sign fp16 [KH wide]
//  blocks 1024..1033: S2W[c][0..1023]=sign(w2[c]) f16, A2P[c]=mean|w2[c]|
//  block  1034:       zero colsum/colsumsq, S2W rows 10..15, A2P[10..15]
// ---------------------------------------------------------------------------
__global__ __launch_bounds__(256) void prep_w(const float* __restrict__ w1,
                                              const float* __restrict__ w2,
                                              float* __restrict__ alpha1,
                                              _Float16* __restrict__ S2,
                                              _Float16* __restrict__ S2W,
                                              float* __restrict__ A2P,
                                              float* __restrict__ colz) {
  __shared__ float red[4];
  const int tid = threadIdx.x, lane = tid & 63, wave = tid >> 6;
  const int j = blockIdx.x;
  if (j < H_DIM) {
    const float* wr = w1 + (long)j * IN_DIM;
    float s = 0.f;
    for (int k = tid; k < IN_DIM; k += 256) s += fabsf(wr[k]);
#pragma unroll
    for (int off = 32; off > 0; off >>= 1) s += __shfl_xor(s, off, 64);
    if (lane == 0) red[wave] = s;
    __syncthreads();
    if (tid == 0) alpha1[j] = (red[0] + red[1] + red[2] + red[3]) * (1.f / IN_DIM);
    _Float16* dr = S2 + (long)j * KH;
    for (int k = tid; k < KH; k += 256) {
      const float v = (k < IN_DIM) ? wr[k] : 0.f;
      dr[k] = (_Float16)((v > 0.f) ? 1.f : ((v < 0.f) ? -1.f : 0.f));
    }
  } else if (j < H_DIM + C_DIM) {
    const int c = j - H_DIM;
    const float* wr = w2 + (long)c * H_DIM;
    float s = 0.f;
    for (int k = tid; k < H_DIM; k += 256) s += fabsf(wr[k]);
#pragma unroll
    for (int off = 32; off > 0; off >>= 1) s += __shfl_xor(s, off, 64);
    if (lane == 0) red[wave] = s;
    __syncthreads();
    if (tid == 0) A2P[c] = (red[0] + red[1] + red[2] + red[3]) * (1.f / H_DIM);
    for (int k = tid; k < H_DIM; k += 256) {
      const float v = wr[k];
      S2W[(long)c * H_DIM + k] = (_Float16)((v > 0.f) ? 1.f : ((v < 0.f) ? -1.f : 0.f));
    }
  } else {
    for (int k = tid; k < 2 * H_DIM; k += 256) colz[k] = 0.f;
    for (int k = tid; k < 6 * H_DIM; k += 256) S2W[10 * H_DIM + k] = (_Float16)0.f;
    if (tid < 6) A2P[10 + tid] = 0.f;
  }
}

// ---------------------------------------------------------------------------
// K3: GEMM1  H[b][j] = alpha1[j]*(Xhi@B + Xlo@B),  M=65536, N=1024, K=800x2.
//
// R9: single-barrier/step + deferred conversion (fixes R5's critical-path
// stall; R5's 2-barrier lockstep anti-correlated LDS and matrix pipes).
//  - per step t: [vmcnt(6); barrier] -> B-DMA(t+2) -> A-loads r(t+3) ->
//    convert r(t+2)+ds_write -> frag reads(t) -> 64 MFMA. One barrier only:
//    waves drift within the step, overlapping one wave's MFMA with another's
//    reads/converts.
//  - A-loads consumed a FULL step after issue (ping-pong f32 reg sets rE/rO,
//    unroll-by-2 for static reg indexing). B-DMA issued FIRST each step, so
//    the conversion's implicit vmcnt wait (in-order) never drains younger
//    B-DMAs: at top of t, queue = [A(t+2)x4, B(t+1)x2] -> vmcnt(6) keeps both
//    in flight while guaranteeing B(t) landed.
//  - slot safety (3-slot ring): writes at step t target slot (t+2)%3 =
//    (t-1)%3, whose readers (step t-1) completed reads before arriving at the
//    top-of-t barrier (their lgkm wait precedes their MFMAs). A-ds_writes are
//    drained by the writer's own later frag-read lgkm wait, two barriers
//    before the readers.
//  - tail: t=22 stages tile 24 (no A-loads); t=23 nothing; t=24 vmcnt(0).
// ---------------------------------------------------------------------------
__global__ __launch_bounds__(512) void gemm1(const float* __restrict__ x,
                                             const _Float16* __restrict__ S2,
                                             const float* __restrict__ alpha1,
                                             float* __restrict__ H,
                                             float* __restrict__ colsum,
                                             float* __restrict__ colsumsq) {
  __shared__ _Float16 lds[3 * SLOT];   // 3 slots x {Ahi|Alo|B} = 144 KiB
  const int tid  = threadIdx.x;
  const int lane = tid & 63;
  const int w    = tid >> 6;
  const int wr   = w >> 2;              // 0..1  (M dir, 128 rows each)
  const int wc   = w & 3;               // 0..3  (N dir, 64 cols each)

  const int b     = blockIdx.x;
  const int xcd   = b & 7;
  const int local = b >> 3;
  const long m0   = (long)(xcd * 32 + (local >> 2)) * 256;
  const int  n0   = (local & 3) * 256;

  // A staging (reg-staged from x): row = tid>>1, half = tid&1 (16 f32 each)
  const int rowS  = tid >> 1;
  const int halfS = tid & 1;
  const float* xp = x + (m0 + rowS) * (long)IN_DIM;
  const int sA = (rowS >> 1) & 3;                 // write-side swizzle
  const int c0 = (halfS * 2) ^ sA;
  const int c1 = (halfS * 2 + 1) ^ sA;
  const int aw = rowS * 32;

  // B staging (DMA): swizzled global source chunk, linear LDS dest
  const int c8 = ((lane & 3) ^ ((lane >> 3) & 3)) * 8;
  const _Float16* bG = S2 + (long)(n0 + w * 32 + (lane >> 2)) * KH + c8;
  const int ldsW0 = (w * 32) * 32;
  const int ldsW1 = (w * 32 + 16) * 32;

  // read-side frag offsets (verified conflict-free swizzle family)
  const int fr = lane & 15;
  const int kc = lane >> 4;
  const int cp = (kc ^ ((fr >> 1) & 3)) * 8;
  const int aoff = (wr * 128 + fr) * 32 + cp;     // + mi*512
  const int boff = (wc * 64 + fr) * 32 + cp;      // + ni*512

  f32x4 acc[8][4] = {};
  f32x4 rE[4], rO[4];

#define CONV_WRITE(RC, PW, KB) do {                                          \
    const bool vldc = ((KB) + halfS * 16) <= (IN_DIM - 16);                  \
    half8 hh0 = {}, hh1 = {}, hl0 = {}, hl1 = {};                            \
    if (vldc) {                                                              \
      _Pragma("unroll")                                                      \
      for (int i = 0; i < 8; ++i) {                                          \
        const float f0 = (i < 4) ? (RC)[0][i & 3] : (RC)[1][i & 3];          \
        const float f1 = (i < 4) ? (RC)[2][i & 3] : (RC)[3][i & 3];          \
        const _Float16 h0 = (_Float16)f0, h1 = (_Float16)f1;                 \
        hh0[i] = h0; hl0[i] = (_Float16)(f0 - (float)h0);                    \
        hh1[i] = h1; hl1[i] = (_Float16)(f1 - (float)h1);                    \
      }                                                                      \
    }                                                                        \
    *(half8*)((PW) + aw + c0 * 8) = hh0;                                     \
    *(half8*)((PW) + aw + c1 * 8) = hh1;                                     \
    *(half8*)((PW) + 8192 + aw + c0 * 8) = hl0;                              \
    *(half8*)((PW) + 8192 + aw + c1 * 8) = hl1;                              \
  } while (0)

#define ALOAD(RL, KL) do {                                                   \
    if (((KL) + halfS * 16) <= (IN_DIM - 16)) {                              \
      const float* src = xp + (KL) + halfS * 16;                             \
      (RL)[0] = *(const f32x4*)(src);                                        \
      (RL)[1] = *(const f32x4*)(src + 4);                                    \
      (RL)[2] = *(const f32x4*)(src + 8);                                    \
      (RL)[3] = *(const f32x4*)(src + 12);                                   \
    } else {                                                                 \
      (RL)[0] = f32x4{}; (RL)[1] = f32x4{}; (RL)[2] = f32x4{}; (RL)[3] = f32x4{}; \
    }                                                                        \
  } while (0)

#define GSTEP(T, RLOAD, RCONV, DO_STAGE, DO_LOAD, VM) do {                   \
    asm volatile("s_waitcnt vmcnt(" #VM ")" ::: "memory");                   \
    __builtin_amdgcn_s_barrier();                                            \
    asm volatile("" ::: "memory");                                           \
    _Float16* Scur = &lds[((T) % 3) * SLOT];                                 \
    if (DO_STAGE) {                                                          \
      _Float16* Pw = &lds[(((T) + 2) % 3) * SLOT];                           \
      const int kb = ((T) + 2) * 32;                                         \
      stage16(bG + kb,           Pw + 16384 + ldsW0, lane);                  \
      stage16(bG + 16 * KH + kb, Pw + 16384 + ldsW1, lane);                  \
      if (DO_LOAD) { ALOAD(RLOAD, ((T) + 3) * 32); }                         \
      CONV_WRITE(RCONV, Pw, kb);                                             \
    }                                                                        \
    half8 af[8], bf[4];                                                      \
    _Pragma("unroll")                                                        \
    for (int ni = 0; ni < 4; ++ni) bf[ni] = *(const half8*)&Scur[16384 + boff + ni * 512]; \
    _Pragma("unroll")                                                        \
    for (int mi = 0; mi < 8; ++mi) af[mi] = *(const half8*)&Scur[aoff + mi * 512]; \
    __builtin_amdgcn_s_setprio(1);                                           \
    _Pragma("unroll")                                                        \
    for (int mi = 0; mi < 8; ++mi)                                           \
      _Pragma("unroll")                                                      \
      for (int ni = 0; ni < 4; ++ni)                                         \
        acc[mi][ni] = __builtin_amdgcn_mfma_f32_16x16x32_f16(af[mi], bf[ni], acc[mi][ni], 0, 0, 0); \
    __builtin_amdgcn_s_setprio(0);                                           \
    _Pragma("unroll")                                                        \
    for (int mi = 0; mi < 8; ++mi) af[mi] = *(const half8*)&Scur[8192 + aoff + mi * 512]; \
    __builtin_amdgcn_s_setprio(1);                                           \
    _Pragma("unroll")                                                        \
    for (int mi = 0; mi < 8; ++mi)                                           \
      _Pragma("unroll")                                                      \
      for (int ni = 0; ni < 4; ++ni)                                         \
        acc[mi][ni] = __builtin_amdgcn_mfma_f32_16x16x32_f16(af[mi], bf[ni], acc[mi][ni], 0, 0, 0); \
    __builtin_amdgcn_s_setprio(0);                                           \
  } while (0)

  // ---- prologue: tiles 0,1 fully staged; r(2) preloaded into rO
  stage16(bG + 0,                 lds + 16384 + ldsW0, lane);
  stage16(bG + 16 * KH + 0,       lds + 16384 + ldsW1, lane);
  stage16(bG + 32,                lds + SLOT + 16384 + ldsW0, lane);
  stage16(bG + 16 * KH + 32,      lds + SLOT + 16384 + ldsW1, lane);
  {
    f32x4 rt[4];
    ALOAD(rt, 0);
    CONV_WRITE(rt, (&lds[0]), 0);
    ALOAD(rt, 32);
    CONV_WRITE(rt, (&lds[SLOT]), 32);
  }
  ALOAD(rO, 64);                       // r(2)
  asm volatile("s_waitcnt lgkmcnt(0)" ::: "memory");  // drain A-writes pre-loop

  // ---- main: t = 0..21 (stage+load), unrolled x2 for reg ping-pong
  for (int tp = 0; tp < 11; ++tp) {
    const int t0 = tp * 2;
    GSTEP(t0,     rE, rO, 1, 1, 6);    // even: load->rE, convert rO
    GSTEP(t0 + 1, rO, rE, 1, 1, 6);    // odd:  load->rO, convert rE
  }
  GSTEP(22, rE, rO, 1, 0, 6);          // stage tile 24 (convert rO=r(24)), no loads
  GSTEP(23, rE, rO, 0, 0, 6);
  GSTEP(24, rE, rO, 0, 0, 0);

  asm volatile("s_waitcnt vmcnt(0)" ::: "memory");   // safety drain

  // epilogue: D layout col=lane&15, row=(lane>>4)*4+r + fused col sum/sumsq
  const int rq = (lane >> 4) * 4;
#pragma unroll
  for (int ni = 0; ni < 4; ++ni) {
    const int col = n0 + wc * 64 + ni * 16 + fr;
    const float a1 = alpha1[col];
    float s = 0.f, q = 0.f;
#pragma unroll
    for (int mi = 0; mi < 8; ++mi) {
#pragma unroll
      for (int r = 0; r < 4; ++r) {
        const long row = m0 + wr * 128 + mi * 16 + rq + r;
        const float v = acc[mi][ni][r] * a1;
        H[row * H_DIM + col] = v;
        s += v;
        q += v * v;
      }
    }
    s += __shfl_xor(s, 16, 64);
    s += __shfl_xor(s, 32, 64);
    q += __shfl_xor(q, 16, 64);
    q += __shfl_xor(q, 32, 64);
    if ((lane >> 4) == 0) {
      atomicAdd(&colsum[col], s);
      atomicAdd(&colsumsq[col], q);
    }
  }
#undef GSTEP
#undef ALOAD
#undef CONV_WRITE
}

// ---------------------------------------------------------------------------
// K5 (R9): normalize -> sign -> GEMM2 via MFMA. Zero shuffles.
// Wave owns a 16-row m-tile; k-loop 32 steps of K=32:
//   A-frag: lane l holds sign(c*h+t) for row (l&15), k=(l>>4)*8+i — built
//     in-register from a coalesced 32B/lane H read (lanes l,l+16,l+32,l+48
//     cover 128B of one row).
//   B-frag: sign(w2) f16 from LDS (32KB), chunk-swizzled cc^(oc&7) (uniform
//     8-lanes/bank = b128 floor).
//   D: row=(l>>4)*4+r, col=(l&15)=oc [measured m89/m91]; epilogue *alpha2
//     in f32 (integer-exact MFMA sums -> more accurate than reference).
// 1024 blocks x 4 waves; ~40KB LDS -> 4 blocks/CU, 16 waves/CU.
// ---------------------------------------------------------------------------
__global__ __launch_bounds__(256) void final_k(const float* __restrict__ H,
                                               const float* __restrict__ colsum,
                                               const float* __restrict__ colsumsq,
                                               const float* __restrict__ gamma,
                                               const float* __restrict__ beta,
                                               const _Float16* __restrict__ S2W,
                                               const float* __restrict__ A2P,
                                               float* __restrict__ out) {
  __shared__ _Float16 bs[16 * H_DIM];   // 32 KB, swizzled
  __shared__ float cs[H_DIM], ts[H_DIM];
  const int tid = threadIdx.x, lane = tid & 63, wave = tid >> 6;

  {  // cs/ts: one f32x4 per thread covers all 1024 cols
    const int j = tid * 4;
    const f32x4 s  = *(const f32x4*)&colsum[j];
    const f32x4 q  = *(const f32x4*)&colsumsq[j];
    const f32x4 g  = *(const f32x4*)&gamma[j];
    const f32x4 bt = *(const f32x4*)&beta[j];
    f32x4 c, t;
#pragma unroll
    for (int i = 0; i < 4; ++i) {
      const float mu  = s[i] * (1.f / BATCH);
      const float var = q[i] * (1.f / BATCH) - mu * mu;
      c[i] = g[i] * rsqrtf(var + BN_EPS);
      t[i] = bt[i] - c[i] * mu;
    }
    *(f32x4*)&cs[j] = c;
    *(f32x4*)&ts[j] = t;
  }
  for (int i = tid; i < 2048; i += 256) {       // 16 rows x 128 chunks of 8 halves
    const int oc = i >> 7, cc = i & 127;
    *(half8*)&bs[oc * H_DIM + ((cc ^ (oc & 7)) << 3)] = *(const half8*)&S2W[oc * H_DIM + (cc << 3)];
  }
  __syncthreads();

  const int lr = lane & 15, lg = lane >> 4;
  const float alf = A2P[lr];
  const long r0 = ((long)blockIdx.x * 4 + wave) * 16;   // grid = BATCH/64
  const float* hp = H + (r0 + lr) * H_DIM + lg * 8;
  const int swz = ((lg) ^ (lr & 7));                    // base chunk xor for bs

  f32x4 acc = {};
#pragma unroll 4
  for (int ks = 0; ks < 32; ++ks) {
    const f32x4 h0 = *(const f32x4*)(hp + ks * 32);
    const f32x4 h1 = *(const f32x4*)(hp + ks * 32 + 4);
    const int jb = ks * 32 + lg * 8;
    const f32x4 c0v = *(const f32x4*)&cs[jb];
    const f32x4 c1v = *(const f32x4*)&cs[jb + 4];
    const f32x4 t0v = *(const f32x4*)&ts[jb];
    const f32x4 t1v = *(const f32x4*)&ts[jb + 4];
    half8 afr;
#pragma unroll
    for (int i = 0; i < 4; ++i) {
      const float hv = h0[i] * c0v[i] + t0v[i];
      afr[i] = (_Float16)((hv > 0.f) ? 1.f : ((hv < 0.f) ? -1.f : 0.f));
    }
#pragma unroll
    for (int i = 0; i < 4; ++i) {
      const float hv = h1[i] * c1v[i] + t1v[i];
      afr[4 + i] = (_Float16)((hv > 0.f) ? 1.f : ((hv < 0.f) ? -1.f : 0.f));
    }
    const int cc = (ks * 4 + lg) ^ (lr & 7);
    const half8 bfr = *(const half8*)&bs[lr * H_DIM + cc * 8];
    acc = __builtin_amdgcn_mfma_f32_16x16x32_f16(afr, bfr, acc, 0, 0, 0);
  }
  (void)swz;

  if (lr < C_DIM) {
#pragma unroll
    for (int r = 0; r < 4; ++r)
      out[(r0 + lg * 4 + r) * C_DIM + lr] = acc[r] * alf;
  }
}

// ---------------------------------------------------------------------------
extern "C" void kernel_launch(void* const* d_in, const int* in_sizes, int n_in,
                              void* d_out, int out_size, void* d_ws, size_t ws_size,
                              hipStream_t stream) {
  const float* x     = (const float*)d_in[0];
  const float* w1    = (const float*)d_in[1];
  const float* w2    = (const float*)d_in[2];
  const float* gamma = (const float*)d_in[3];
  const float* beta  = (const float*)d_in[4];
  float* out = (float*)d_out;

  // workspace layout (bytes), 256B-aligned; total ~270.1 MB
  char* ws = (char*)d_ws;
  float*    H      = (float*)   (ws + 0);             // 268,435,456
  _Float16* S2     = (_Float16*)(ws + 268435456LL);   // 1024*800*2 = 1,638,400
  _Float16* S2W    = (_Float16*)(ws + 270073856LL);   // 16*1024*2  =    32,768
  float*    ALPHA1 = (float*)   (ws + 270106624LL);   // 1024*4
  float*    A2P    = (float*)   (ws + 270110720LL);   // 16*4 (pad to 256)
  float*    COLS   = (float*)   (ws + 270110976LL);   // 1024*4
  float*    COLQ   = (float*)   (ws + 270115072LL);   // 1024*4

  prep_w<<<H_DIM + C_DIM + 1, 256, 0, stream>>>(w1, w2, ALPHA1, S2, S2W, A2P, COLS);
  gemm1<<<1024, 512, 0, stream>>>(x, S2, ALPHA1, H, COLS, COLQ);
  final_k<<<BATCH / 64, 256, 0, stream>>>(H, COLS, COLQ, gamma, beta, S2W, A2P, out);
}